// Round 11
// baseline (260.979 us; speedup 1.0000x reference)
//
#include <hip/hip_runtime.h>

#define NN 50000
#define NE 800000
#define DIM 128
#define NG 64
#define ETOT (NE + NN)
#define NEG_SLOPE 0.2f
#define PB 200          // pooling blocks; chunk = 250 nodes
#define MAXLG 8         // local graph slots per block
#define NSH 8           // dst shards (== XCDs)
#define SHW ((NN + NSH - 1) / NSH)   // 6250 nodes per shard
#define NB_SCAN ((NN + 255) / 256)   // 196
#define CAP 512         // staged edges per 4-node block (mean 68; P(>512) ~ 0)

typedef unsigned int uint32;
typedef unsigned short ushort;
typedef short bf16x8 __attribute__((ext_vector_type(8)));
typedef float f32x4 __attribute__((ext_vector_type(4)));

static __device__ __forceinline__ uint32 f2bf_pack(float lo, float hi) {
  uint32 a = __float_as_uint(lo), b = __float_as_uint(hi);
  a = (a + 0x7fffu + ((a >> 16) & 1u)) >> 16;          // RNE
  b = (b + 0x7fffu + ((b >> 16) & 1u)) >> 16;
  return a | (b << 16);
}
static __device__ __forceinline__ ushort f2bf1(float x) {
  uint32 a = __float_as_uint(x);
  a = (a + 0x7fffu + ((a >> 16) & 1u)) >> 16;
  return (ushort)a;
}
static __device__ __forceinline__ float bf_lo(uint32 u) { return __uint_as_float(u << 16); }
static __device__ __forceinline__ float bf_hi(uint32 u) { return __uint_as_float(u & 0xffff0000u); }

// ============================ init + weight prep (fused) ============================

__global__ __launch_bounds__(256) void k_init(const float* __restrict__ W1, const float* __restrict__ W2,
                                              ushort* __restrict__ wt1, ushort* __restrict__ wt2,
                                              int* deg, int* fill, float* pooled, float* cnt) {
  int i = blockIdx.x * 256 + threadIdx.x;
  if (i < NN) { deg[i] = 1; fill[i] = 1; }          // 1 = self-loop
  if (i < NG * DIM) pooled[i] = 0.f;
  if (i < NG) cnt[i] = 0.f;
  if (i < DIM * DIM) {                              // W^T bf16 rows (contiguous k) for MFMA B-frags
    int n = i >> 7, k = i & 127;
    wt1[i] = f2bf1(W1[k * DIM + n]);
    wt2[i] = f2bf1(W2[k * DIM + n]);
  }
}

__global__ __launch_bounds__(256) void k_count(const int* __restrict__ dst, int* __restrict__ deg) {
  int e = blockIdx.x * 256 + threadIdx.x;
  if (e < NE) atomicAdd(&deg[dst[e]], 1);
}

// ---- 3-phase multi-block inclusive scan: offs[i+1] = sum(deg[0..i]) ----

__global__ __launch_bounds__(256) void k_scan1(const int* __restrict__ deg, int* __restrict__ offs,
                                               int* __restrict__ bsum) {
  __shared__ int ws[4];
  const int i = blockIdx.x * 256 + threadIdx.x;
  const int lane = threadIdx.x & 63, wid = threadIdx.x >> 6;
  int x = (i < NN) ? deg[i] : 0;
#pragma unroll
  for (int off = 1; off < 64; off <<= 1) {
    int t = __shfl_up(x, off, 64);
    if (lane >= off) x += t;
  }
  if (lane == 63) ws[wid] = x;
  __syncthreads();
  int pre = 0;
#pragma unroll
  for (int j = 0; j < 3; ++j) if (j < wid) pre += ws[j];
  x += pre;
  if (i < NN) offs[i + 1] = x;
  if (threadIdx.x == 255) bsum[blockIdx.x] = x;
}

__global__ __launch_bounds__(256) void k_scan2(const int* __restrict__ bsum, int* __restrict__ bpre) {
  __shared__ int ws[4];
  const int b = threadIdx.x;
  const int lane = b & 63, wid = b >> 6;
  int v = (b < NB_SCAN) ? bsum[b] : 0;
  int x = v;
#pragma unroll
  for (int off = 1; off < 64; off <<= 1) {
    int t = __shfl_up(x, off, 64);
    if (lane >= off) x += t;
  }
  if (lane == 63) ws[wid] = x;
  __syncthreads();
  int pre = 0;
#pragma unroll
  for (int j = 0; j < 3; ++j) if (j < wid) pre += ws[j];
  x += pre;
  if (b < NB_SCAN) bpre[b] = x - v;     // exclusive prefix of block totals
}

// scan3 + self-loop placement fused: slot offs[i] == offs[i+1] - deg[i]
__global__ __launch_bounds__(256) void k_scan3(int* __restrict__ offs, const int* __restrict__ bpre,
                                               const int* __restrict__ deg, int* __restrict__ csr) {
  const int i = blockIdx.x * 256 + threadIdx.x;
  if (i < NN) {
    int v = offs[i + 1] + bpre[blockIdx.x];
    offs[i + 1] = v;
    csr[v - deg[i]] = i;                // slot 0 of each segment = self-loop
  }
  if (i == 0) offs[0] = 0;
}

// XCD-sharded scatter (round-5 notes): each csr line dirtied by one XCD only.
__global__ __launch_bounds__(256) void k_scatter(const int* __restrict__ src, const int* __restrict__ dst,
                                                 const int* __restrict__ offs, int* __restrict__ fill,
                                                 int* __restrict__ csr) {
  const int r = blockIdx.x & (NSH - 1);
  const int bi = blockIdx.x >> 3;
  const int nb = gridDim.x >> 3;
  const int lo = r * SHW, hi = min(lo + SHW, NN);
  for (int e = bi * 256 + threadIdx.x; e < NE; e += nb * 256) {
    int d = dst[e];
    if (d >= lo && d < hi) {
      int p = offs[d] + atomicAdd(&fill[d], 1);
      csr[p] = src[e];
    }
  }
}

// ============== MFMA GEMM: {Hlo,Hhi} = bf16(X @ W) split by feature half; alpha fused ==============
// A16=1 -> X given as split bf16 halves (Xlo/Xhi); A16=0 -> X is f32 full rows.

template <int A16>
__global__ __launch_bounds__(256) void k_mm(const void* __restrict__ Xlo_v, const void* __restrict__ Xhi_v,
                                            const ushort* __restrict__ WT,
                                            const float* __restrict__ a_s, const float* __restrict__ a_d,
                                            uint32* __restrict__ Hlo, uint32* __restrict__ Hhi,
                                            float* __restrict__ alpha_s, float* __restrict__ alpha_d, int n) {
  __shared__ __align__(16) ushort sWT[DIM * DIM];   // 32 KB
  __shared__ __align__(16) ushort sA[64 * DIM];     // 16 KB
  const int tid = threadIdx.x;
  const int row0 = blockIdx.x * 64;

  {  // stage W^T -> LDS (swizzled)
    const int nr = tid >> 1, h2 = tid & 1;
    const uint4* wp = (const uint4*)(WT + nr * DIM + h2 * 64);
#pragma unroll
    for (int i = 0; i < 8; ++i) {
      uint4 v = wp[i];
      int byte = nr * 256 + (((h2 * 128 + i * 16)) ^ ((nr & 7) << 4));
      *(uint4*)((char*)sWT + byte) = v;
    }
  }
  {  // stage A -> LDS (bf16, swizzled)
    const int r = tid >> 2, q = tid & 3;
    int rg = row0 + r; if (rg > n - 1) rg = n - 1;
    if (A16) {
      const uint32* srcb = (q < 2) ? (const uint32*)Xlo_v : (const uint32*)Xhi_v;
      const uint4* xp = (const uint4*)(srcb + (size_t)rg * 32 + (q & 1) * 16);
#pragma unroll
      for (int i = 0; i < 4; ++i) {
        uint4 pk = xp[i];
        int byte = r * 256 + ((q * 64 + i * 16) ^ ((r & 7) << 4));
        *(uint4*)((char*)sA + byte) = pk;
      }
    } else {
      const float4* xp = (const float4*)((const float*)Xlo_v + (size_t)rg * DIM + q * 32);
#pragma unroll
      for (int i = 0; i < 4; ++i) {
        float4 v0 = xp[2 * i], v1 = xp[2 * i + 1];
        uint4 pk = make_uint4(f2bf_pack(v0.x, v0.y), f2bf_pack(v0.z, v0.w),
                              f2bf_pack(v1.x, v1.y), f2bf_pack(v1.z, v1.w));
        int byte = r * 256 + ((q * 64 + i * 16) ^ ((r & 7) << 4));
        *(uint4*)((char*)sA + byte) = pk;
      }
    }
  }
  __syncthreads();

  const int l = tid & 63, wv = tid >> 6;
  const int jr = l & 15, g = l >> 4;
  const int m0 = wv * 16;
  f32x4 acc[8];
#pragma unroll
  for (int nt = 0; nt < 8; ++nt) acc[nt] = (f32x4){0.f, 0.f, 0.f, 0.f};

  const int ra = m0 + jr;
  const int abase = ra * 256, aswz = (ra & 7) << 4;
  const int bswz = (jr & 7) << 4;
#pragma unroll
  for (int kk = 0; kk < 4; ++kk) {
    const int kb = kk * 64 + g * 16;
    bf16x8 af = *(const bf16x8*)((const char*)sA + abase + (kb ^ aswz));
#pragma unroll
    for (int nt = 0; nt < 8; ++nt) {
      bf16x8 bfg = *(const bf16x8*)((const char*)sWT + (nt * 16 + jr) * 256 + (kb ^ bswz));
      acc[nt] = __builtin_amdgcn_mfma_f32_16x16x32_bf16(af, bfg, acc[nt], 0, 0, 0);
    }
  }

  // fused alpha from f32 accumulators: row = m0 + g*4 + j, col = nt*16 + jr
  float asv[8], adv[8];
#pragma unroll
  for (int nt = 0; nt < 8; ++nt) { asv[nt] = a_s[nt * 16 + jr]; adv[nt] = a_d[nt * 16 + jr]; }
#pragma unroll
  for (int j = 0; j < 4; ++j) {
    float ps = 0.f, pd = 0.f;
#pragma unroll
    for (int nt = 0; nt < 8; ++nt) {
      ps = fmaf(acc[nt][j], asv[nt], ps);
      pd = fmaf(acc[nt][j], adv[nt], pd);
    }
#pragma unroll
    for (int off = 1; off < 16; off <<= 1) {
      ps += __shfl_xor(ps, off, 64);
      pd += __shfl_xor(pd, off, 64);
    }
    int r = row0 + m0 + g * 4 + j;
    if (jr == 0 && r < n) { alpha_s[r] = ps; alpha_d[r] = pd; }
  }

  // bf16 output bounce through this wave's own sA rows, then coalesced split-half stores
  ushort* sOut = sA;
#pragma unroll
  for (int nt = 0; nt < 8; ++nt)
#pragma unroll
    for (int j = 0; j < 4; ++j)
      sOut[(m0 + g * 4 + j) * DIM + nt * 16 + jr] = f2bf1(acc[nt][j]);
#pragma unroll
  for (int i = 0; i < 4; ++i) {
    int r = row0 + m0 + (l >> 4) + i * 4;
    uint4 v = *(const uint4*)((const char*)sOut + m0 * 256 + l * 16 + i * 1024);
    if (r < n) {
      int c = (l & 15) * 4;                       // uint col 0..60
      uint32* dstb = (c < 32) ? Hlo : Hhi;
      *(uint4*)(dstb + (size_t)r * 32 + (c & 31)) = v;
    }
  }
}

// ============ fused edge-softmax + aggregation v5: half-feature split, 2 edges/wave-inst ============
// Grid = 2 * NN/4 blocks; half = blockIdx&1 (even/odd XCD under round-robin -> per-XCD
// footprint 6.4MB). Block stages its 4 nodes' (src, alpha) pairs once (duplicated across
// the parity pair), each wave softmaxes its own node, then gathers with lanes 0-31 on
// edge j and lanes 32-63 on edge j+1 -- 2 edges per instruction, 128B half-row each.
// Cross-group __shfl_xor(32) merges the two partial sums.

template <int STORE16>
__global__ __launch_bounds__(256) void k_sma(const int* __restrict__ offs, const int* __restrict__ csr,
                                             const float* __restrict__ alpha_s, const float* __restrict__ alpha_d,
                                             const uint32* __restrict__ Hlo, const uint32* __restrict__ Hhi,
                                             const float* __restrict__ bias,
                                             float* __restrict__ out,
                                             uint32* __restrict__ f1lo, uint32* __restrict__ f1hi) {
  __shared__ int2 s_pair[CAP];          // (src, alpha|ex)
  __shared__ int s_off[5];
  const int tid = threadIdx.x;
  const int half = blockIdx.x & 1;
  const int n0 = (blockIdx.x >> 1) * 4;
  if (tid <= 4) s_off[tid] = offs[n0 + tid];
  __syncthreads();
  const int ebeg = s_off[0];
  const int nE = s_off[4] - ebeg;
  const int l = tid & 63, wv = tid >> 6;
  const int sl = l & 31, g = l >> 5;
  const int node = n0 + wv;
  const uint32* __restrict__ Hh = half ? Hhi : Hlo;
  const float2 bb = *(const float2*)(bias + half * 64 + 2 * sl);
  float ax = 0.f, ay = 0.f, inv;

  if (nE <= CAP) {
    // ---- phase 1: stage (all 256 threads) ----
    for (int e = tid; e < nE; e += 256) {
      int sv = csr[ebeg + e];
      s_pair[e] = make_int2(sv, __float_as_int(alpha_s[sv]));
    }
    __syncthreads();
    // ---- phase 2: per-wave softmax over own range ----
    const int jb = s_off[wv] - ebeg, je = s_off[wv + 1] - ebeg;
    const int cnt = je - jb;
    const float ad = alpha_d[node];
    float m = -1e30f;
    for (int j = jb + l; j < je; j += 64) {
      float sc = __int_as_float(s_pair[j].y) + ad;
      sc = sc > 0.f ? sc : NEG_SLOPE * sc;
      m = fmaxf(m, sc);
    }
#pragma unroll
    for (int off = 1; off < 64; off <<= 1) m = fmaxf(m, __shfl_xor(m, off, 64));
    float ssum = 0.f;
    for (int j = jb + l; j < je; j += 64) {
      float sc = __int_as_float(s_pair[j].y) + ad;
      sc = sc > 0.f ? sc : NEG_SLOPE * sc;
      float ex = __expf(sc - m);
      s_pair[j].y = __float_as_int(ex);
      ssum += ex;
    }
#pragma unroll
    for (int off = 1; off < 64; off <<= 1) ssum += __shfl_xor(ssum, off, 64);
    inv = 1.f / (ssum + 1e-16f);
    // ---- gather: 2 edges per instruction (lane-group g -> edge j+g) ----
    int j = 0;
    for (; j + 4 <= cnt; j += 4) {
      int2 pA = s_pair[jb + j + g];
      int2 pB = s_pair[jb + j + 2 + g];
      uint32 vA = Hh[((uint32)pA.x << 5) + sl];
      uint32 vB = Hh[((uint32)pB.x << 5) + sl];
      float cA = __int_as_float(pA.y), cB = __int_as_float(pB.y);
      ax = fmaf(cA, bf_lo(vA), ax); ay = fmaf(cA, bf_hi(vA), ay);
      ax = fmaf(cB, bf_lo(vB), ax); ay = fmaf(cB, bf_hi(vB), ay);
    }
    for (; j < cnt; j += 2) {
      int jj = j + g;
      bool va = jj < cnt;
      int2 p = s_pair[jb + (va ? jj : 0)];
      float c = va ? __int_as_float(p.y) : 0.f;
      uint32 v = Hh[((uint32)p.x << 5) + sl];
      ax = fmaf(c, bf_lo(v), ax); ay = fmaf(c, bf_hi(v), ay);
    }
    // merge edge-parity partials
    ax += __shfl_xor(ax, 32, 64);
    ay += __shfl_xor(ay, 32, 64);
  } else {
    // ---- fallback: direct per-node two-pass from global (nE > CAP; essentially never) ----
    const int bg = offs[node], eg = offs[node + 1];
    const float ad = alpha_d[node];
    float m = -1e30f;
    for (int jj = bg + l; jj < eg; jj += 64) {
      float sc = alpha_s[csr[jj]] + ad;
      sc = sc > 0.f ? sc : NEG_SLOPE * sc;
      m = fmaxf(m, sc);
    }
#pragma unroll
    for (int off = 1; off < 64; off <<= 1) m = fmaxf(m, __shfl_xor(m, off, 64));
    const uint32* __restrict__ Hme = (l < 32) ? Hlo : Hhi;   // full row across the wave
    float ssum = 0.f;
    for (int base = bg; base < eg; base += 64) {
      int cnt = min(64, eg - base);
      int sv = 0; float ex = 0.f;
      if (l < cnt) {
        sv = csr[base + l];
        float sc = alpha_s[sv] + ad;
        sc = sc > 0.f ? sc : NEG_SLOPE * sc;
        ex = __expf(sc - m);
      }
      ssum += ex;
      for (int jj = 0; jj < cnt; ++jj) {
        int s0 = __shfl(sv, jj, 64); float c0 = __shfl(ex, jj, 64);
        uint32 v0 = Hme[((uint32)s0 << 5) + sl];
        ax = fmaf(c0, bf_lo(v0), ax); ay = fmaf(c0, bf_hi(v0), ay);
      }
    }
#pragma unroll
    for (int off = 1; off < 64; off <<= 1) ssum += __shfl_xor(ssum, off, 64);
    inv = 1.f / (ssum + 1e-16f);
    // move the block's half into lanes 0-31
    float tx = __shfl(ax, half * 32 + sl, 64);
    float ty = __shfl(ay, half * 32 + sl, 64);
    ax = tx; ay = ty;
  }

  if (l < 32) {
    const float ox = ax * inv + bb.x, oy = ay * inv + bb.y;
    if (STORE16) {
      uint32* f1h = half ? f1hi : f1lo;
      f1h[(uint32)node * 32 + sl] = f2bf_pack(ox, oy);
    } else {
      *(float2*)(out + (size_t)node * DIM + half * 64 + 2 * sl) = make_float2(ox, oy);
    }
  }
}

// ============================ global mean pool (hierarchical, batch sorted) ============================

__global__ __launch_bounds__(256) void k_pool_partial(const float* __restrict__ feats,
                                                      const int* __restrict__ batch,
                                                      float* __restrict__ pooled, float* __restrict__ cnt) {
  __shared__ float acc[4][MAXLG][DIM];
  __shared__ float lcnt[4][MAXLG];
  const int tid = threadIdx.x;
  const int wid = tid >> 6, l = tid & 63;
  for (int i = tid; i < 4 * MAXLG * DIM; i += 256) ((float*)acc)[i] = 0.f;
  if (tid < 4 * MAXLG) ((float*)lcnt)[tid] = 0.f;
  __syncthreads();

  const int chunk = (NN + PB - 1) / PB;
  const int beg = blockIdx.x * chunk;
  const int end = min(beg + chunk, NN);
  const int g0 = (beg < NN) ? batch[beg] : 0;

  for (int node = beg + wid; node < end; node += 4) {
    int lg = batch[node] - g0;
    float2 v = *(const float2*)(feats + (size_t)node * DIM + 2 * l);
    if (lg < MAXLG) {
      acc[wid][lg][2 * l] += v.x;
      acc[wid][lg][2 * l + 1] += v.y;
      if (l == 0) lcnt[wid][lg] += 1.f;
    } else {
      atomicAdd(&pooled[(g0 + lg) * DIM + 2 * l], v.x);
      atomicAdd(&pooled[(g0 + lg) * DIM + 2 * l + 1], v.y);
      if (l == 0) atomicAdd(&cnt[g0 + lg], 1.f);
    }
  }
  __syncthreads();

  for (int i = tid; i < MAXLG * DIM; i += 256) {
    int lg = i >> 7, d = i & (DIM - 1);
    float s = acc[0][lg][d] + acc[1][lg][d] + acc[2][lg][d] + acc[3][lg][d];
    if (s != 0.f) atomicAdd(&pooled[(g0 + lg) * DIM + d], s);
  }
  if (tid < MAXLG) {
    float s = lcnt[0][tid] + lcnt[1][tid] + lcnt[2][tid] + lcnt[3][tid];
    if (s != 0.f) atomicAdd(&cnt[g0 + tid], s);
  }
}

__global__ __launch_bounds__(256) void k_pool_norm(float* pooled, const float* __restrict__ cnt) {
  int i = blockIdx.x * 256 + threadIdx.x;
  if (i < NG * DIM) pooled[i] /= fmaxf(cnt[i >> 7], 1.f);
}

// ============================ launch ============================

static inline size_t pad256(size_t x) { return (x + 255) & ~(size_t)255; }

extern "C" void kernel_launch(void* const* d_in, const int* in_sizes, int n_in,
                              void* d_out, int out_size, void* d_ws, size_t ws_size,
                              hipStream_t stream) {
  const float* x   = (const float*)d_in[0];
  const int* ei    = (const int*)d_in[1];
  const int* batch = (const int*)d_in[2];
  const float* W1  = (const float*)d_in[3];
  const float* as1 = (const float*)d_in[4];
  const float* ad1 = (const float*)d_in[5];
  const float* b1  = (const float*)d_in[6];
  const float* W2  = (const float*)d_in[7];
  const float* as2 = (const float*)d_in[8];
  const float* ad2 = (const float*)d_in[9];
  const float* b2  = (const float*)d_in[10];

  float* out_feats = (float*)d_out;
  float* pooled    = out_feats + (size_t)NN * DIM;

  const int* src = ei;
  const int* dst = ei + NE;

  char* w = (char*)d_ws;
  uint32* hlo  = (uint32*)w;  w += pad256((size_t)NN * 32 * 4);    // bf16 h, features 0-63 (6.4 MB)
  uint32* hhi  = (uint32*)w;  w += pad256((size_t)NN * 32 * 4);    // bf16 h, features 64-127
  uint32* f1lo = (uint32*)w;  w += pad256((size_t)NN * 32 * 4);    // bf16 layer-1 out halves
  uint32* f1hi = (uint32*)w;  w += pad256((size_t)NN * 32 * 4);
  float* alpha_s = (float*)w; w += pad256((size_t)NN * 4);
  float* alpha_d = (float*)w; w += pad256((size_t)NN * 4);
  int* deg  = (int*)w;        w += pad256((size_t)NN * 4);
  int* offs = (int*)w;        w += pad256((size_t)(NN + 1) * 4);
  int* fill = (int*)w;        w += pad256((size_t)NN * 4);
  int* csr  = (int*)w;        w += pad256((size_t)ETOT * 4);
  float* cnt  = (float*)w;    w += pad256((size_t)NG * 4);
  int* bsum = (int*)w;        w += pad256((size_t)NB_SCAN * 4);
  int* bpre = (int*)w;        w += pad256((size_t)NB_SCAN * 4);
  ushort* wt1 = (ushort*)w;   w += pad256((size_t)DIM * DIM * 2);
  ushort* wt2 = (ushort*)w;   w += pad256((size_t)DIM * DIM * 2);

  const int NB_N = (NN + 255) / 256;
  const int NB_E = (NE + 255) / 256;
  const int NB_A = (NN / 4) * 2;                // 25000 blocks: 4 nodes x 2 feature halves
  const int NB_G = (NN + 63) / 64;
  const int NB_SC = 1024;                       // sharded scatter: 128 blocks x 8 shards

  // CSR build + weight prep (graph shared by both layers)
  k_init<<<NB_N, 256, 0, stream>>>(W1, W2, wt1, wt2, deg, fill, pooled, cnt);
  k_count<<<NB_E, 256, 0, stream>>>(dst, deg);
  k_scan1<<<NB_SCAN, 256, 0, stream>>>(deg, offs, bsum);
  k_scan2<<<1, 256, 0, stream>>>(bsum, bpre);
  k_scan3<<<NB_SCAN, 256, 0, stream>>>(offs, bpre, deg, csr);   // + self-loop placement
  k_scatter<<<NB_SC, 256, 0, stream>>>(src, dst, offs, fill, csr);

  // layer 1
  k_mm<0><<<NB_G, 256, 0, stream>>>(x, nullptr, wt1, as1, ad1, hlo, hhi, alpha_s, alpha_d, NN);
  k_sma<1><<<NB_A, 256, 0, stream>>>(offs, csr, alpha_s, alpha_d, hlo, hhi, b1, nullptr, f1lo, f1hi);

  // layer 2
  k_mm<1><<<NB_G, 256, 0, stream>>>(f1lo, f1hi, wt2, as2, ad2, hlo, hhi, alpha_s, alpha_d, NN);
  k_sma<0><<<NB_A, 256, 0, stream>>>(offs, csr, alpha_s, alpha_d, hlo, hhi, b2, out_feats, nullptr, nullptr);

  // pool
  k_pool_partial<<<PB, 256, 0, stream>>>(out_feats, batch, pooled, cnt);
  k_pool_norm<<<(NG * DIM + 255) / 256, 256, 0, stream>>>(pooled, cnt);
}

// Round 12
// 213.598 us; speedup vs baseline: 1.2218x; 1.2218x over previous
//
#include <hip/hip_runtime.h>

#define NN 50000
#define NE 800000
#define DIM 128
#define NG 64
#define ETOT (NE + NN)
#define NEG_SLOPE 0.2f
#define PB 200          // pooling blocks; chunk = 250 nodes
#define MAXLG 8         // local graph slots per block
#define NSH 8           // dst shards (== XCDs)
#define SHW ((NN + NSH - 1) / NSH)   // 6250 nodes per shard
#define NB_SCAN ((NN + 255) / 256)   // 196

typedef unsigned int uint32;
typedef unsigned short ushort;
typedef short bf16x8 __attribute__((ext_vector_type(8)));
typedef float f32x4 __attribute__((ext_vector_type(4)));

static __device__ __forceinline__ uint32 f2bf_pack(float lo, float hi) {
  uint32 a = __float_as_uint(lo), b = __float_as_uint(hi);
  a = (a + 0x7fffu + ((a >> 16) & 1u)) >> 16;          // RNE
  b = (b + 0x7fffu + ((b >> 16) & 1u)) >> 16;
  return a | (b << 16);
}
static __device__ __forceinline__ ushort f2bf1(float x) {
  uint32 a = __float_as_uint(x);
  a = (a + 0x7fffu + ((a >> 16) & 1u)) >> 16;
  return (ushort)a;
}
static __device__ __forceinline__ float bf_lo(uint32 u) { return __uint_as_float(u << 16); }
static __device__ __forceinline__ float bf_hi(uint32 u) { return __uint_as_float(u & 0xffff0000u); }

// ============================ init + weight prep (fused) ============================

__global__ __launch_bounds__(256) void k_init(const float* __restrict__ W1, const float* __restrict__ W2,
                                              ushort* __restrict__ wt1, ushort* __restrict__ wt2,
                                              int* deg, int* fill, float* pooled, float* cnt) {
  int i = blockIdx.x * 256 + threadIdx.x;
  if (i < NN) { deg[i] = 1; fill[i] = 1; }          // 1 = self-loop
  if (i < NG * DIM) pooled[i] = 0.f;
  if (i < NG) cnt[i] = 0.f;
  if (i < DIM * DIM) {                              // W^T bf16 rows (contiguous k) for MFMA B-frags
    int n = i >> 7, k = i & 127;
    wt1[i] = f2bf1(W1[k * DIM + n]);
    wt2[i] = f2bf1(W2[k * DIM + n]);
  }
}

__global__ __launch_bounds__(256) void k_count(const int* __restrict__ dst, int* __restrict__ deg) {
  int e = blockIdx.x * 256 + threadIdx.x;
  if (e < NE) atomicAdd(&deg[dst[e]], 1);
}

// ---- 3-phase multi-block inclusive scan: offs[i+1] = sum(deg[0..i]) ----

__global__ __launch_bounds__(256) void k_scan1(const int* __restrict__ deg, int* __restrict__ offs,
                                               int* __restrict__ bsum) {
  __shared__ int ws[4];
  const int i = blockIdx.x * 256 + threadIdx.x;
  const int lane = threadIdx.x & 63, wid = threadIdx.x >> 6;
  int x = (i < NN) ? deg[i] : 0;
#pragma unroll
  for (int off = 1; off < 64; off <<= 1) {
    int t = __shfl_up(x, off, 64);
    if (lane >= off) x += t;
  }
  if (lane == 63) ws[wid] = x;
  __syncthreads();
  int pre = 0;
#pragma unroll
  for (int j = 0; j < 3; ++j) if (j < wid) pre += ws[j];
  x += pre;
  if (i < NN) offs[i + 1] = x;
  if (threadIdx.x == 255) bsum[blockIdx.x] = x;
}

__global__ __launch_bounds__(256) void k_scan2(const int* __restrict__ bsum, int* __restrict__ bpre) {
  __shared__ int ws[4];
  const int b = threadIdx.x;
  const int lane = b & 63, wid = b >> 6;
  int v = (b < NB_SCAN) ? bsum[b] : 0;
  int x = v;
#pragma unroll
  for (int off = 1; off < 64; off <<= 1) {
    int t = __shfl_up(x, off, 64);
    if (lane >= off) x += t;
  }
  if (lane == 63) ws[wid] = x;
  __syncthreads();
  int pre = 0;
#pragma unroll
  for (int j = 0; j < 3; ++j) if (j < wid) pre += ws[j];
  x += pre;
  if (b < NB_SCAN) bpre[b] = x - v;     // exclusive prefix of block totals
}

// scan3 + self-loop placement fused: slot offs[i] == offs[i+1] - deg[i]
__global__ __launch_bounds__(256) void k_scan3(int* __restrict__ offs, const int* __restrict__ bpre,
                                               const int* __restrict__ deg, int* __restrict__ csr) {
  const int i = blockIdx.x * 256 + threadIdx.x;
  if (i < NN) {
    int v = offs[i + 1] + bpre[blockIdx.x];
    offs[i + 1] = v;
    csr[v - deg[i]] = i;                // slot 0 of each segment = self-loop
  }
  if (i == 0) offs[0] = 0;
}

// XCD-sharded scatter (round-5 notes): each csr line dirtied by one XCD only.
__global__ __launch_bounds__(256) void k_scatter(const int* __restrict__ src, const int* __restrict__ dst,
                                                 const int* __restrict__ offs, int* __restrict__ fill,
                                                 int* __restrict__ csr) {
  const int r = blockIdx.x & (NSH - 1);
  const int bi = blockIdx.x >> 3;
  const int nb = gridDim.x >> 3;
  const int lo = r * SHW, hi = min(lo + SHW, NN);
  for (int e = bi * 256 + threadIdx.x; e < NE; e += nb * 256) {
    int d = dst[e];
    if (d >= lo && d < hi) {
      int p = offs[d] + atomicAdd(&fill[d], 1);
      csr[p] = src[e];
    }
  }
}

// ============== MFMA GEMM: H16 = bf16(X @ W), alpha fused; A16=1 -> X is bf16-packed ==============

template <int A16>
__global__ __launch_bounds__(256) void k_mm(const void* __restrict__ Xv, const ushort* __restrict__ WT,
                                            const float* __restrict__ a_s, const float* __restrict__ a_d,
                                            uint32* __restrict__ H16,
                                            float* __restrict__ alpha_s, float* __restrict__ alpha_d, int n) {
  __shared__ __align__(16) ushort sWT[DIM * DIM];   // 32 KB
  __shared__ __align__(16) ushort sA[64 * DIM];     // 16 KB
  const int tid = threadIdx.x;
  const int row0 = blockIdx.x * 64;

  {  // stage W^T -> LDS (swizzled)
    const int nr = tid >> 1, h2 = tid & 1;
    const uint4* wp = (const uint4*)(WT + nr * DIM + h2 * 64);
#pragma unroll
    for (int i = 0; i < 8; ++i) {
      uint4 v = wp[i];
      int byte = nr * 256 + (((h2 * 128 + i * 16)) ^ ((nr & 7) << 4));
      *(uint4*)((char*)sWT + byte) = v;
    }
  }
  {  // stage A -> LDS (bf16, swizzled)
    const int r = tid >> 2, q = tid & 3;
    int rg = row0 + r; if (rg > n - 1) rg = n - 1;
    if (A16) {
      const uint4* xp = (const uint4*)((const uint32*)Xv + (size_t)rg * 64 + q * 16);
#pragma unroll
      for (int i = 0; i < 4; ++i) {
        uint4 pk = xp[i];
        int byte = r * 256 + ((q * 64 + i * 16) ^ ((r & 7) << 4));
        *(uint4*)((char*)sA + byte) = pk;
      }
    } else {
      const float4* xp = (const float4*)((const float*)Xv + (size_t)rg * DIM + q * 32);
#pragma unroll
      for (int i = 0; i < 4; ++i) {
        float4 v0 = xp[2 * i], v1 = xp[2 * i + 1];
        uint4 pk = make_uint4(f2bf_pack(v0.x, v0.y), f2bf_pack(v0.z, v0.w),
                              f2bf_pack(v1.x, v1.y), f2bf_pack(v1.z, v1.w));
        int byte = r * 256 + ((q * 64 + i * 16) ^ ((r & 7) << 4));
        *(uint4*)((char*)sA + byte) = pk;
      }
    }
  }
  __syncthreads();

  const int l = tid & 63, wv = tid >> 6;
  const int jr = l & 15, g = l >> 4;
  const int m0 = wv * 16;
  f32x4 acc[8];
#pragma unroll
  for (int nt = 0; nt < 8; ++nt) acc[nt] = (f32x4){0.f, 0.f, 0.f, 0.f};

  const int ra = m0 + jr;
  const int abase = ra * 256, aswz = (ra & 7) << 4;
  const int bswz = (jr & 7) << 4;
#pragma unroll
  for (int kk = 0; kk < 4; ++kk) {
    const int kb = kk * 64 + g * 16;
    bf16x8 af = *(const bf16x8*)((const char*)sA + abase + (kb ^ aswz));
#pragma unroll
    for (int nt = 0; nt < 8; ++nt) {
      bf16x8 bfg = *(const bf16x8*)((const char*)sWT + (nt * 16 + jr) * 256 + (kb ^ bswz));
      acc[nt] = __builtin_amdgcn_mfma_f32_16x16x32_bf16(af, bfg, acc[nt], 0, 0, 0);
    }
  }

  // fused alpha from f32 accumulators: row = m0 + g*4 + j, col = nt*16 + jr
  float asv[8], adv[8];
#pragma unroll
  for (int nt = 0; nt < 8; ++nt) { asv[nt] = a_s[nt * 16 + jr]; adv[nt] = a_d[nt * 16 + jr]; }
#pragma unroll
  for (int j = 0; j < 4; ++j) {
    float ps = 0.f, pd = 0.f;
#pragma unroll
    for (int nt = 0; nt < 8; ++nt) {
      ps = fmaf(acc[nt][j], asv[nt], ps);
      pd = fmaf(acc[nt][j], adv[nt], pd);
    }
#pragma unroll
    for (int off = 1; off < 16; off <<= 1) {
      ps += __shfl_xor(ps, off, 64);
      pd += __shfl_xor(pd, off, 64);
    }
    int r = row0 + m0 + g * 4 + j;
    if (jr == 0 && r < n) { alpha_s[r] = ps; alpha_d[r] = pd; }
  }

  // bf16 output bounce through this wave's own sA rows, then coalesced stores
  ushort* sOut = sA;
#pragma unroll
  for (int nt = 0; nt < 8; ++nt)
#pragma unroll
    for (int j = 0; j < 4; ++j)
      sOut[(m0 + g * 4 + j) * DIM + nt * 16 + jr] = f2bf1(acc[nt][j]);
#pragma unroll
  for (int i = 0; i < 4; ++i) {
    int r = row0 + m0 + (l >> 4) + i * 4;
    uint4 v = *(const uint4*)((const char*)sOut + m0 * 256 + l * 16 + i * 1024);
    if (r < n) *(uint4*)(H16 + (size_t)(row0 + m0) * 64 + l * 4 + i * 256) = v;
  }
}

// ============ fused edge-softmax + aggregation (round-8 champion structure) ============
// 2 nodes per wave (32 lanes each), half feature row per block (half = blockIdx&1;
// round-robin block->XCD dispatch makes each XCD touch only one 128B half of every
// h16 row -> 6.4MB per-XCD footprint). (src, ex) broadcast via shfl; 8-deep unroll
// for outstanding-load depth. Locality-only; any block->XCD mapping stays correct.

#define GATHER4(J)                                                          \
  { int s0 = __shfl(sv, g32 + (J), 64), s1 = __shfl(sv, g32 + (J) + 1, 64), \
        s2 = __shfl(sv, g32 + (J) + 2, 64), s3 = __shfl(sv, g32 + (J) + 3, 64); \
    float c0 = __shfl(ex, g32 + (J), 64), c1 = __shfl(ex, g32 + (J) + 1, 64), \
          c2 = __shfl(ex, g32 + (J) + 2, 64), c3 = __shfl(ex, g32 + (J) + 3, 64); \
    uint32 v0 = H16[(size_t)s0 * 64 + u0];                                  \
    uint32 v1 = H16[(size_t)s1 * 64 + u0];                                  \
    uint32 v2 = H16[(size_t)s2 * 64 + u0];                                  \
    uint32 v3 = H16[(size_t)s3 * 64 + u0];                                  \
    ax = fmaf(c0, bf_lo(v0), ax); ay = fmaf(c0, bf_hi(v0), ay);             \
    ax = fmaf(c1, bf_lo(v1), ax); ay = fmaf(c1, bf_hi(v1), ay);             \
    ax = fmaf(c2, bf_lo(v2), ax); ay = fmaf(c2, bf_hi(v2), ay);             \
    ax = fmaf(c3, bf_lo(v3), ax); ay = fmaf(c3, bf_hi(v3), ay); }

#define GATHER1(J)                                                          \
  { int s0 = __shfl(sv, g32 + (J), 64); float c0 = __shfl(ex, g32 + (J), 64); \
    uint32 v0 = H16[(size_t)s0 * 64 + u0];                                  \
    ax = fmaf(c0, bf_lo(v0), ax); ay = fmaf(c0, bf_hi(v0), ay); }

template <int STORE16>
__global__ __launch_bounds__(256) void k_sm_aggr2(const int* __restrict__ offs, const int* __restrict__ csr,
                                                  const float* __restrict__ alpha_s, const float* __restrict__ alpha_d,
                                                  const uint32* __restrict__ H16, const float* __restrict__ bias,
                                                  float* __restrict__ out, uint32* __restrict__ out16) {
  const int b = blockIdx.x;
  const int half = b & 1;                        // == XCD parity under round-robin dispatch
  const int l = threadIdx.x & 63;
  const int sl = l & 31, g = l >> 5, g32 = g * 32;
  const int pair = (b >> 1) * 4 + (threadIdx.x >> 6);   // 0..24999
  const int node = pair * 2 + g;
  const int bg = offs[node], eg = offs[node + 1];
  const int dg = eg - bg;
  const float ad = alpha_d[node];
  const int u0 = half * 32 + sl;                 // uint index within the row

  const int maxd = max(dg, __shfl_xor(dg, 32, 64));
  float ax = 0.f, ay = 0.f, ssum = 0.f;

  if (maxd <= 32) {                              // fast path (~99.9% of pairs)
    int sv = 0; float sc = -1e30f;
    if (sl < dg) {
      sv = csr[bg + sl];
      sc = alpha_s[sv] + ad;
      sc = sc > 0.f ? sc : NEG_SLOPE * sc;
    }
    float m = sc;
#pragma unroll
    for (int off = 1; off < 32; off <<= 1) m = fmaxf(m, __shfl_xor(m, off, 64));
    float ex = (sl < dg) ? __expf(sc - m) : 0.f;
    ssum = ex;
    int j = 0;
    for (; j + 7 < maxd; j += 8) { GATHER4(j); GATHER4(j + 4); }   // 8 outstanding loads
    for (; j + 3 < maxd; j += 4) GATHER4(j);
    for (; j < maxd; ++j) GATHER1(j);
  } else {                                       // chunked general path
    float m = -1e30f;
    for (int j = sl; j < dg; j += 32) {
      float sc = alpha_s[csr[bg + j]] + ad;
      sc = sc > 0.f ? sc : NEG_SLOPE * sc;
      m = fmaxf(m, sc);
    }
#pragma unroll
    for (int off = 1; off < 32; off <<= 1) m = fmaxf(m, __shfl_xor(m, off, 64));
    const int nch = (maxd + 31) >> 5;
    for (int c = 0; c < nch; ++c) {
      int j = c * 32 + sl;
      int sv = 0; float ex = 0.f;
      if (j < dg) {
        sv = csr[bg + j];
        float sc = alpha_s[sv] + ad;
        sc = sc > 0.f ? sc : NEG_SLOPE * sc;
        ex = __expf(sc - m);
      }
      ssum += ex;
      int cnt = min(32, maxd - c * 32);
      int jj = 0;
      for (; jj + 3 < cnt; jj += 4) GATHER4(jj);
      for (; jj < cnt; ++jj) GATHER1(jj);
    }
  }

#pragma unroll
  for (int off = 1; off < 32; off <<= 1) ssum += __shfl_xor(ssum, off, 64);
  const float inv = 1.f / (ssum + 1e-16f);
  const float2 bb = *(const float2*)(bias + 2 * u0);
  const float ox = ax * inv + bb.x, oy = ay * inv + bb.y;
  if (STORE16) {
    out16[(size_t)node * 64 + u0] = f2bf_pack(ox, oy);
  } else {
    *(float2*)(out + (size_t)node * DIM + 2 * u0) = make_float2(ox, oy);
  }
}

// ============================ global mean pool (hierarchical, batch sorted) ============================

__global__ __launch_bounds__(256) void k_pool_partial(const float* __restrict__ feats,
                                                      const int* __restrict__ batch,
                                                      float* __restrict__ pooled, float* __restrict__ cnt) {
  __shared__ float acc[4][MAXLG][DIM];
  __shared__ float lcnt[4][MAXLG];
  const int tid = threadIdx.x;
  const int wid = tid >> 6, l = tid & 63;
  for (int i = tid; i < 4 * MAXLG * DIM; i += 256) ((float*)acc)[i] = 0.f;
  if (tid < 4 * MAXLG) ((float*)lcnt)[tid] = 0.f;
  __syncthreads();

  const int chunk = (NN + PB - 1) / PB;
  const int beg = blockIdx.x * chunk;
  const int end = min(beg + chunk, NN);
  const int g0 = (beg < NN) ? batch[beg] : 0;

  for (int node = beg + wid; node < end; node += 4) {
    int lg = batch[node] - g0;
    float2 v = *(const float2*)(feats + (size_t)node * DIM + 2 * l);
    if (lg < MAXLG) {
      acc[wid][lg][2 * l] += v.x;
      acc[wid][lg][2 * l + 1] += v.y;
      if (l == 0) lcnt[wid][lg] += 1.f;
    } else {
      atomicAdd(&pooled[(g0 + lg) * DIM + 2 * l], v.x);
      atomicAdd(&pooled[(g0 + lg) * DIM + 2 * l + 1], v.y);
      if (l == 0) atomicAdd(&cnt[g0 + lg], 1.f);
    }
  }
  __syncthreads();

  for (int i = tid; i < MAXLG * DIM; i += 256) {
    int lg = i >> 7, d = i & (DIM - 1);
    float s = acc[0][lg][d] + acc[1][lg][d] + acc[2][lg][d] + acc[3][lg][d];
    if (s != 0.f) atomicAdd(&pooled[(g0 + lg) * DIM + d], s);
  }
  if (tid < MAXLG) {
    float s = lcnt[0][tid] + lcnt[1][tid] + lcnt[2][tid] + lcnt[3][tid];
    if (s != 0.f) atomicAdd(&cnt[g0 + tid], s);
  }
}

__global__ __launch_bounds__(256) void k_pool_norm(float* pooled, const float* __restrict__ cnt) {
  int i = blockIdx.x * 256 + threadIdx.x;
  if (i < NG * DIM) pooled[i] /= fmaxf(cnt[i >> 7], 1.f);
}

// ============================ launch ============================

static inline size_t pad256(size_t x) { return (x + 255) & ~(size_t)255; }

extern "C" void kernel_launch(void* const* d_in, const int* in_sizes, int n_in,
                              void* d_out, int out_size, void* d_ws, size_t ws_size,
                              hipStream_t stream) {
  const float* x   = (const float*)d_in[0];
  const int* ei    = (const int*)d_in[1];
  const int* batch = (const int*)d_in[2];
  const float* W1  = (const float*)d_in[3];
  const float* as1 = (const float*)d_in[4];
  const float* ad1 = (const float*)d_in[5];
  const float* b1  = (const float*)d_in[6];
  const float* W2  = (const float*)d_in[7];
  const float* as2 = (const float*)d_in[8];
  const float* ad2 = (const float*)d_in[9];
  const float* b2  = (const float*)d_in[10];

  float* out_feats = (float*)d_out;
  float* pooled    = out_feats + (size_t)NN * DIM;

  const int* src = ei;
  const int* dst = ei + NE;

  char* w = (char*)d_ws;
  uint32* h16 = (uint32*)w;   w += pad256((size_t)NN * 64 * 4);    // bf16-packed h (12.8 MB)
  uint32* f116 = (uint32*)w;  w += pad256((size_t)NN * 64 * 4);    // bf16-packed layer-1 out
  float* alpha_s = (float*)w; w += pad256((size_t)NN * 4);
  float* alpha_d = (float*)w; w += pad256((size_t)NN * 4);
  int* deg  = (int*)w;        w += pad256((size_t)NN * 4);
  int* offs = (int*)w;        w += pad256((size_t)(NN + 1) * 4);
  int* fill = (int*)w;        w += pad256((size_t)NN * 4);
  int* csr  = (int*)w;        w += pad256((size_t)ETOT * 4);
  float* cnt  = (float*)w;    w += pad256((size_t)NG * 4);
  int* bsum = (int*)w;        w += pad256((size_t)NB_SCAN * 4);
  int* bpre = (int*)w;        w += pad256((size_t)NB_SCAN * 4);
  ushort* wt1 = (ushort*)w;   w += pad256((size_t)DIM * DIM * 2);
  ushort* wt2 = (ushort*)w;   w += pad256((size_t)DIM * DIM * 2);

  const int NB_N = (NN + 255) / 256;
  const int NB_E = (NE + 255) / 256;
  const int NB_A = (NN / 2 / 4) * 2;            // 12500: 25000 pairs x 2 halves / 4 waves
  const int NB_G = (NN + 63) / 64;
  const int NB_SC = 1024;                       // sharded scatter: 128 blocks x 8 shards

  // CSR build + weight prep (graph shared by both layers)
  k_init<<<NB_N, 256, 0, stream>>>(W1, W2, wt1, wt2, deg, fill, pooled, cnt);
  k_count<<<NB_E, 256, 0, stream>>>(dst, deg);
  k_scan1<<<NB_SCAN, 256, 0, stream>>>(deg, offs, bsum);
  k_scan2<<<1, 256, 0, stream>>>(bsum, bpre);
  k_scan3<<<NB_SCAN, 256, 0, stream>>>(offs, bpre, deg, csr);   // + self-loop placement
  k_scatter<<<NB_SC, 256, 0, stream>>>(src, dst, offs, fill, csr);

  // layer 1
  k_mm<0><<<NB_G, 256, 0, stream>>>(x, wt1, as1, ad1, h16, alpha_s, alpha_d, NN);
  k_sm_aggr2<1><<<NB_A, 256, 0, stream>>>(offs, csr, alpha_s, alpha_d, h16, b1, nullptr, f116);

  // layer 2
  k_mm<1><<<NB_G, 256, 0, stream>>>(f116, wt2, as2, ad2, h16, alpha_s, alpha_d, NN);
  k_sm_aggr2<0><<<NB_A, 256, 0, stream>>>(offs, csr, alpha_s, alpha_d, h16, b2, out_feats, nullptr);

  // pool
  k_pool_partial<<<PB, 256, 0, stream>>>(out_feats, batch, pooled, cnt);
  k_pool_norm<<<(NG * DIM + 255) / 256, 256, 0, stream>>>(pooled, cnt);
}

// Round 13
// 209.941 us; speedup vs baseline: 1.2431x; 1.0174x over previous
//
#include <hip/hip_runtime.h>

#define NN 50000
#define NE 800000
#define DIM 128
#define NG 64
#define ETOT (NE + NN)
#define NEG_SLOPE 0.2f
#define PB 200          // pooling blocks; chunk = 250 nodes
#define MAXLG 8         // local graph slots per block
#define NSH 8           // dst shards (== XCDs)
#define SHW ((NN + NSH - 1) / NSH)   // 6250 nodes per shard
#define NB_SCAN ((NN + 255) / 256)   // 196

typedef unsigned int uint32;
typedef unsigned short ushort;
typedef short bf16x8 __attribute__((ext_vector_type(8)));
typedef float f32x4 __attribute__((ext_vector_type(4)));

static __device__ __forceinline__ uint32 f2bf_pack(float lo, float hi) {
  uint32 a = __float_as_uint(lo), b = __float_as_uint(hi);
  a = (a + 0x7fffu + ((a >> 16) & 1u)) >> 16;          // RNE
  b = (b + 0x7fffu + ((b >> 16) & 1u)) >> 16;
  return a | (b << 16);
}
static __device__ __forceinline__ ushort f2bf1(float x) {
  uint32 a = __float_as_uint(x);
  a = (a + 0x7fffu + ((a >> 16) & 1u)) >> 16;
  return (ushort)a;
}
static __device__ __forceinline__ float bf_lo(uint32 u) { return __uint_as_float(u << 16); }
static __device__ __forceinline__ float bf_hi(uint32 u) { return __uint_as_float(u & 0xffff0000u); }

// ============================ init + weight prep (fused) ============================

__global__ __launch_bounds__(256) void k_init(const float* __restrict__ W1, const float* __restrict__ W2,
                                              ushort* __restrict__ wt1, ushort* __restrict__ wt2,
                                              int* deg, int* fill, float* pooled, float* cnt) {
  int i = blockIdx.x * 256 + threadIdx.x;
  if (i < NN) { deg[i] = 1; fill[i] = 1; }          // 1 = self-loop
  if (i < NG * DIM) pooled[i] = 0.f;
  if (i < NG) cnt[i] = 0.f;
  if (i < DIM * DIM) {                              // W^T bf16 rows (contiguous k) for MFMA B-frags
    int n = i >> 7, k = i & 127;
    wt1[i] = f2bf1(W1[k * DIM + n]);
    wt2[i] = f2bf1(W2[k * DIM + n]);
  }
}

__global__ __launch_bounds__(256) void k_count(const int* __restrict__ dst, int* __restrict__ deg) {
  int e = blockIdx.x * 256 + threadIdx.x;
  if (e < NE) atomicAdd(&deg[dst[e]], 1);
}

// ---- 3-phase multi-block inclusive scan: offs[i+1] = sum(deg[0..i]) ----

__global__ __launch_bounds__(256) void k_scan1(const int* __restrict__ deg, int* __restrict__ offs,
                                               int* __restrict__ bsum) {
  __shared__ int ws[4];
  const int i = blockIdx.x * 256 + threadIdx.x;
  const int lane = threadIdx.x & 63, wid = threadIdx.x >> 6;
  int x = (i < NN) ? deg[i] : 0;
#pragma unroll
  for (int off = 1; off < 64; off <<= 1) {
    int t = __shfl_up(x, off, 64);
    if (lane >= off) x += t;
  }
  if (lane == 63) ws[wid] = x;
  __syncthreads();
  int pre = 0;
#pragma unroll
  for (int j = 0; j < 3; ++j) if (j < wid) pre += ws[j];
  x += pre;
  if (i < NN) offs[i + 1] = x;
  if (threadIdx.x == 255) bsum[blockIdx.x] = x;
}

__global__ __launch_bounds__(256) void k_scan2(const int* __restrict__ bsum, int* __restrict__ bpre) {
  __shared__ int ws[4];
  const int b = threadIdx.x;
  const int lane = b & 63, wid = b >> 6;
  int v = (b < NB_SCAN) ? bsum[b] : 0;
  int x = v;
#pragma unroll
  for (int off = 1; off < 64; off <<= 1) {
    int t = __shfl_up(x, off, 64);
    if (lane >= off) x += t;
  }
  if (lane == 63) ws[wid] = x;
  __syncthreads();
  int pre = 0;
#pragma unroll
  for (int j = 0; j < 3; ++j) if (j < wid) pre += ws[j];
  x += pre;
  if (b < NB_SCAN) bpre[b] = x - v;     // exclusive prefix of block totals
}

// scan3 + self-loop placement fused: slot offs[i] == offs[i+1] - deg[i]
__global__ __launch_bounds__(256) void k_scan3(int* __restrict__ offs, const int* __restrict__ bpre,
                                               const int* __restrict__ deg, int* __restrict__ csr) {
  const int i = blockIdx.x * 256 + threadIdx.x;
  if (i < NN) {
    int v = offs[i + 1] + bpre[blockIdx.x];
    offs[i + 1] = v;
    csr[v - deg[i]] = i;                // slot 0 of each segment = self-loop
  }
  if (i == 0) offs[0] = 0;
}

// XCD-sharded scatter (round-5 notes): each csr line dirtied by one XCD only.
__global__ __launch_bounds__(256) void k_scatter(const int* __restrict__ src, const int* __restrict__ dst,
                                                 const int* __restrict__ offs, int* __restrict__ fill,
                                                 int* __restrict__ csr) {
  const int r = blockIdx.x & (NSH - 1);
  const int bi = blockIdx.x >> 3;
  const int nb = gridDim.x >> 3;
  const int lo = r * SHW, hi = min(lo + SHW, NN);
  for (int e = bi * 256 + threadIdx.x; e < NE; e += nb * 256) {
    int d = dst[e];
    if (d >= lo && d < hi) {
      int p = offs[d] + atomicAdd(&fill[d], 1);
      csr[p] = src[e];
    }
  }
}

// ============== MFMA GEMM: H16 = bf16(X @ W), alpha fused; A16=1 -> X is bf16-packed ==============

template <int A16>
__global__ __launch_bounds__(256) void k_mm(const void* __restrict__ Xv, const ushort* __restrict__ WT,
                                            const float* __restrict__ a_s, const float* __restrict__ a_d,
                                            uint32* __restrict__ H16,
                                            float* __restrict__ alpha_s, float* __restrict__ alpha_d, int n) {
  __shared__ __align__(16) ushort sWT[DIM * DIM];   // 32 KB
  __shared__ __align__(16) ushort sA[64 * DIM];     // 16 KB
  const int tid = threadIdx.x;
  const int row0 = blockIdx.x * 64;

  {  // stage W^T -> LDS (swizzled)
    const int nr = tid >> 1, h2 = tid & 1;
    const uint4* wp = (const uint4*)(WT + nr * DIM + h2 * 64);
#pragma unroll
    for (int i = 0; i < 8; ++i) {
      uint4 v = wp[i];
      int byte = nr * 256 + (((h2 * 128 + i * 16)) ^ ((nr & 7) << 4));
      *(uint4*)((char*)sWT + byte) = v;
    }
  }
  {  // stage A -> LDS (bf16, swizzled)
    const int r = tid >> 2, q = tid & 3;
    int rg = row0 + r; if (rg > n - 1) rg = n - 1;
    if (A16) {
      const uint4* xp = (const uint4*)((const uint32*)Xv + (size_t)rg * 64 + q * 16);
#pragma unroll
      for (int i = 0; i < 4; ++i) {
        uint4 pk = xp[i];
        int byte = r * 256 + ((q * 64 + i * 16) ^ ((r & 7) << 4));
        *(uint4*)((char*)sA + byte) = pk;
      }
    } else {
      const float4* xp = (const float4*)((const float*)Xv + (size_t)rg * DIM + q * 32);
#pragma unroll
      for (int i = 0; i < 4; ++i) {
        float4 v0 = xp[2 * i], v1 = xp[2 * i + 1];
        uint4 pk = make_uint4(f2bf_pack(v0.x, v0.y), f2bf_pack(v0.z, v0.w),
                              f2bf_pack(v1.x, v1.y), f2bf_pack(v1.z, v1.w));
        int byte = r * 256 + ((q * 64 + i * 16) ^ ((r & 7) << 4));
        *(uint4*)((char*)sA + byte) = pk;
      }
    }
  }
  __syncthreads();

  const int l = tid & 63, wv = tid >> 6;
  const int jr = l & 15, g = l >> 4;
  const int m0 = wv * 16;
  f32x4 acc[8];
#pragma unroll
  for (int nt = 0; nt < 8; ++nt) acc[nt] = (f32x4){0.f, 0.f, 0.f, 0.f};

  const int ra = m0 + jr;
  const int abase = ra * 256, aswz = (ra & 7) << 4;
  const int bswz = (jr & 7) << 4;
#pragma unroll
  for (int kk = 0; kk < 4; ++kk) {
    const int kb = kk * 64 + g * 16;
    bf16x8 af = *(const bf16x8*)((const char*)sA + abase + (kb ^ aswz));
#pragma unroll
    for (int nt = 0; nt < 8; ++nt) {
      bf16x8 bfg = *(const bf16x8*)((const char*)sWT + (nt * 16 + jr) * 256 + (kb ^ bswz));
      acc[nt] = __builtin_amdgcn_mfma_f32_16x16x32_bf16(af, bfg, acc[nt], 0, 0, 0);
    }
  }

  // fused alpha from f32 accumulators: row = m0 + g*4 + j, col = nt*16 + jr
  float asv[8], adv[8];
#pragma unroll
  for (int nt = 0; nt < 8; ++nt) { asv[nt] = a_s[nt * 16 + jr]; adv[nt] = a_d[nt * 16 + jr]; }
#pragma unroll
  for (int j = 0; j < 4; ++j) {
    float ps = 0.f, pd = 0.f;
#pragma unroll
    for (int nt = 0; nt < 8; ++nt) {
      ps = fmaf(acc[nt][j], asv[nt], ps);
      pd = fmaf(acc[nt][j], adv[nt], pd);
    }
#pragma unroll
    for (int off = 1; off < 16; off <<= 1) {
      ps += __shfl_xor(ps, off, 64);
      pd += __shfl_xor(pd, off, 64);
    }
    int r = row0 + m0 + g * 4 + j;
    if (jr == 0 && r < n) { alpha_s[r] = ps; alpha_d[r] = pd; }
  }

  // bf16 output bounce through this wave's own sA rows, then coalesced stores
  ushort* sOut = sA;
#pragma unroll
  for (int nt = 0; nt < 8; ++nt)
#pragma unroll
    for (int j = 0; j < 4; ++j)
      sOut[(m0 + g * 4 + j) * DIM + nt * 16 + jr] = f2bf1(acc[nt][j]);
#pragma unroll
  for (int i = 0; i < 4; ++i) {
    int r = row0 + m0 + (l >> 4) + i * 4;
    uint4 v = *(const uint4*)((const char*)sOut + m0 * 256 + l * 16 + i * 1024);
    if (r < n) *(uint4*)(H16 + (size_t)(row0 + m0) * 64 + l * 4 + i * 256) = v;
  }
}

// ============ fused edge-softmax + aggregation v6: 2 nodes/wave, uint2 full-row gather ============
// Lanes 0-31 own node A, lanes 32-63 node B. Each 32-lane group covers the FULL 256B
// feature row via uint2 (8B/lane) -> one load instruction serves 2 edges x 256B = 512B.
// Softmax done once per node (no parity duplication); (src, ex) broadcast via shfl;
// 8-deep unrolled gather for outstanding-load depth.

#define GATHER2(J)                                                          \
  { int s0 = __shfl(sv, g32 + (J), 64), s1 = __shfl(sv, g32 + (J) + 1, 64); \
    float c0 = __shfl(ex, g32 + (J), 64), c1 = __shfl(ex, g32 + (J) + 1, 64); \
    uint2 v0 = *(const uint2*)(H16 + ((size_t)s0 << 6) + su);               \
    uint2 v1 = *(const uint2*)(H16 + ((size_t)s1 << 6) + su);               \
    a0 = fmaf(c0, bf_lo(v0.x), a0); a1 = fmaf(c0, bf_hi(v0.x), a1);         \
    a2 = fmaf(c0, bf_lo(v0.y), a2); a3 = fmaf(c0, bf_hi(v0.y), a3);         \
    a0 = fmaf(c1, bf_lo(v1.x), a0); a1 = fmaf(c1, bf_hi(v1.x), a1);         \
    a2 = fmaf(c1, bf_lo(v1.y), a2); a3 = fmaf(c1, bf_hi(v1.y), a3); }

#define GATHER1(J)                                                          \
  { int s0 = __shfl(sv, g32 + (J), 64); float c0 = __shfl(ex, g32 + (J), 64); \
    uint2 v0 = *(const uint2*)(H16 + ((size_t)s0 << 6) + su);               \
    a0 = fmaf(c0, bf_lo(v0.x), a0); a1 = fmaf(c0, bf_hi(v0.x), a1);         \
    a2 = fmaf(c0, bf_lo(v0.y), a2); a3 = fmaf(c0, bf_hi(v0.y), a3); }

template <int STORE16>
__global__ __launch_bounds__(256) void k_sm_aggr3(const int* __restrict__ offs, const int* __restrict__ csr,
                                                  const float* __restrict__ alpha_s, const float* __restrict__ alpha_d,
                                                  const uint32* __restrict__ H16, const float* __restrict__ bias,
                                                  float* __restrict__ out, uint32* __restrict__ out16) {
  const int l = threadIdx.x & 63;
  const int sl = l & 31, g = l >> 5, g32 = g * 32;
  const int su = sl * 2;                         // uint offset within the row
  const int pair = blockIdx.x * 4 + (threadIdx.x >> 6);   // 0..24999
  const int node = pair * 2 + g;
  const int bg = offs[node], eg = offs[node + 1];
  const int dg = eg - bg;
  const float ad = alpha_d[node];

  const int maxd = max(dg, __shfl_xor(dg, 32, 64));
  float a0 = 0.f, a1 = 0.f, a2 = 0.f, a3 = 0.f, ssum = 0.f;

  if (maxd <= 32) {                              // fast path (~99.9% of pairs)
    int sv = 0; float sc = -1e30f;
    if (sl < dg) {
      sv = csr[bg + sl];
      sc = alpha_s[sv] + ad;
      sc = sc > 0.f ? sc : NEG_SLOPE * sc;
    }
    float m = sc;
#pragma unroll
    for (int off = 1; off < 32; off <<= 1) m = fmaxf(m, __shfl_xor(m, off, 64));
    float ex = (sl < dg) ? __expf(sc - m) : 0.f;
    ssum = ex;
    int j = 0;
    for (; j + 3 < maxd; j += 4) { GATHER2(j); GATHER2(j + 2); }   // 4 uint2 loads in flight
    for (; j + 1 < maxd; j += 2) GATHER2(j);
    for (; j < maxd; ++j) GATHER1(j);
  } else {                                       // chunked general path
    float m = -1e30f;
    for (int j = sl; j < dg; j += 32) {
      float sc = alpha_s[csr[bg + j]] + ad;
      sc = sc > 0.f ? sc : NEG_SLOPE * sc;
      m = fmaxf(m, sc);
    }
#pragma unroll
    for (int off = 1; off < 32; off <<= 1) m = fmaxf(m, __shfl_xor(m, off, 64));
    const int nch = (maxd + 31) >> 5;
    for (int c = 0; c < nch; ++c) {
      int j = c * 32 + sl;
      int sv = 0; float ex = 0.f;
      if (j < dg) {
        sv = csr[bg + j];
        float sc = alpha_s[sv] + ad;
        sc = sc > 0.f ? sc : NEG_SLOPE * sc;
        ex = __expf(sc - m);
      }
      ssum += ex;
      int cnt = min(32, maxd - c * 32);
      int jj = 0;
      for (; jj + 1 < cnt; jj += 2) GATHER2(jj);
      for (; jj < cnt; ++jj) GATHER1(jj);
    }
  }

#pragma unroll
  for (int off = 1; off < 32; off <<= 1) ssum += __shfl_xor(ssum, off, 64);
  const float inv = 1.f / (ssum + 1e-16f);
  const float4 bb = *(const float4*)(bias + 4 * sl);
  const float o0 = a0 * inv + bb.x, o1 = a1 * inv + bb.y;
  const float o2 = a2 * inv + bb.z, o3 = a3 * inv + bb.w;
  if (STORE16) {
    uint2 pv = make_uint2(f2bf_pack(o0, o1), f2bf_pack(o2, o3));
    *(uint2*)(out16 + (size_t)node * 64 + su) = pv;
  } else {
    *(float4*)(out + (size_t)node * DIM + 4 * sl) = make_float4(o0, o1, o2, o3);
  }
}

// ============================ global mean pool (hierarchical, batch sorted) ============================

__global__ __launch_bounds__(256) void k_pool_partial(const float* __restrict__ feats,
                                                      const int* __restrict__ batch,
                                                      float* __restrict__ pooled, float* __restrict__ cnt) {
  __shared__ float acc[4][MAXLG][DIM];
  __shared__ float lcnt[4][MAXLG];
  const int tid = threadIdx.x;
  const int wid = tid >> 6, l = tid & 63;
  for (int i = tid; i < 4 * MAXLG * DIM; i += 256) ((float*)acc)[i] = 0.f;
  if (tid < 4 * MAXLG) ((float*)lcnt)[tid] = 0.f;
  __syncthreads();

  const int chunk = (NN + PB - 1) / PB;
  const int beg = blockIdx.x * chunk;
  const int end = min(beg + chunk, NN);
  const int g0 = (beg < NN) ? batch[beg] : 0;

  for (int node = beg + wid; node < end; node += 4) {
    int lg = batch[node] - g0;
    float2 v = *(const float2*)(feats + (size_t)node * DIM + 2 * l);
    if (lg < MAXLG) {
      acc[wid][lg][2 * l] += v.x;
      acc[wid][lg][2 * l + 1] += v.y;
      if (l == 0) lcnt[wid][lg] += 1.f;
    } else {
      atomicAdd(&pooled[(g0 + lg) * DIM + 2 * l], v.x);
      atomicAdd(&pooled[(g0 + lg) * DIM + 2 * l + 1], v.y);
      if (l == 0) atomicAdd(&cnt[g0 + lg], 1.f);
    }
  }
  __syncthreads();

  for (int i = tid; i < MAXLG * DIM; i += 256) {
    int lg = i >> 7, d = i & (DIM - 1);
    float s = acc[0][lg][d] + acc[1][lg][d] + acc[2][lg][d] + acc[3][lg][d];
    if (s != 0.f) atomicAdd(&pooled[(g0 + lg) * DIM + d], s);
  }
  if (tid < MAXLG) {
    float s = lcnt[0][tid] + lcnt[1][tid] + lcnt[2][tid] + lcnt[3][tid];
    if (s != 0.f) atomicAdd(&cnt[g0 + tid], s);
  }
}

__global__ __launch_bounds__(256) void k_pool_norm(float* pooled, const float* __restrict__ cnt) {
  int i = blockIdx.x * 256 + threadIdx.x;
  if (i < NG * DIM) pooled[i] /= fmaxf(cnt[i >> 7], 1.f);
}

// ============================ launch ============================

static inline size_t pad256(size_t x) { return (x + 255) & ~(size_t)255; }

extern "C" void kernel_launch(void* const* d_in, const int* in_sizes, int n_in,
                              void* d_out, int out_size, void* d_ws, size_t ws_size,
                              hipStream_t stream) {
  const float* x   = (const float*)d_in[0];
  const int* ei    = (const int*)d_in[1];
  const int* batch = (const int*)d_in[2];
  const float* W1  = (const float*)d_in[3];
  const float* as1 = (const float*)d_in[4];
  const float* ad1 = (const float*)d_in[5];
  const float* b1  = (const float*)d_in[6];
  const float* W2  = (const float*)d_in[7];
  const float* as2 = (const float*)d_in[8];
  const float* ad2 = (const float*)d_in[9];
  const float* b2  = (const float*)d_in[10];

  float* out_feats = (float*)d_out;
  float* pooled    = out_feats + (size_t)NN * DIM;

  const int* src = ei;
  const int* dst = ei + NE;

  char* w = (char*)d_ws;
  uint32* h16 = (uint32*)w;   w += pad256((size_t)NN * 64 * 4);    // bf16-packed h (12.8 MB)
  uint32* f116 = (uint32*)w;  w += pad256((size_t)NN * 64 * 4);    // bf16-packed layer-1 out
  float* alpha_s = (float*)w; w += pad256((size_t)NN * 4);
  float* alpha_d = (float*)w; w += pad256((size_t)NN * 4);
  int* deg  = (int*)w;        w += pad256((size_t)NN * 4);
  int* offs = (int*)w;        w += pad256((size_t)(NN + 1) * 4);
  int* fill = (int*)w;        w += pad256((size_t)NN * 4);
  int* csr  = (int*)w;        w += pad256((size_t)ETOT * 4);
  float* cnt  = (float*)w;    w += pad256((size_t)NG * 4);
  int* bsum = (int*)w;        w += pad256((size_t)NB_SCAN * 4);
  int* bpre = (int*)w;        w += pad256((size_t)NB_SCAN * 4);
  ushort* wt1 = (ushort*)w;   w += pad256((size_t)DIM * DIM * 2);
  ushort* wt2 = (ushort*)w;   w += pad256((size_t)DIM * DIM * 2);

  const int NB_N = (NN + 255) / 256;
  const int NB_E = (NE + 255) / 256;
  const int NB_A = NN / 2 / 4;                  // 6250 blocks: 25000 node-pairs / 4 waves
  const int NB_G = (NN + 63) / 64;
  const int NB_SC = 1024;                       // sharded scatter: 128 blocks x 8 shards

  // CSR build + weight prep (graph shared by both layers)
  k_init<<<NB_N, 256, 0, stream>>>(W1, W2, wt1, wt2, deg, fill, pooled, cnt);
  k_count<<<NB_E, 256, 0, stream>>>(dst, deg);
  k_scan1<<<NB_SCAN, 256, 0, stream>>>(deg, offs, bsum);
  k_scan2<<<1, 256, 0, stream>>>(bsum, bpre);
  k_scan3<<<NB_SCAN, 256, 0, stream>>>(offs, bpre, deg, csr);   // + self-loop placement
  k_scatter<<<NB_SC, 256, 0, stream>>>(src, dst, offs, fill, csr);

  // layer 1
  k_mm<0><<<NB_G, 256, 0, stream>>>(x, wt1, as1, ad1, h16, alpha_s, alpha_d, NN);
  k_sm_aggr3<1><<<NB_A, 256, 0, stream>>>(offs, csr, alpha_s, alpha_d, h16, b1, nullptr, f116);

  // layer 2
  k_mm<1><<<NB_G, 256, 0, stream>>>(f116, wt2, as2, ad2, h16, alpha_s, alpha_d, NN);
  k_sm_aggr3<0><<<NB_A, 256, 0, stream>>>(offs, csr, alpha_s, alpha_d, h16, b2, out_feats, nullptr);

  // pool
  k_pool_partial<<<PB, 256, 0, stream>>>(out_feats, batch, pooled, cnt);
  k_pool_norm<<<(NG * DIM + 255) / 256, 256, 0, stream>>>(pooled, cnt);
}